// Round 3
// baseline (307.457 us; speedup 1.0000x reference)
//
#include <hip/hip_runtime.h>
#include <hip/hip_bf16.h>
#include <stdint.h>

// LatticeMultiHeadAttention on MI355X (gfx950). f32 in/out, bf16 MFMA inside.
// Kuramoto phase inputs are softmax-shift-invariant -> unused.
//
// R7: fuse the activation f32->bf16 conversion INTO gemm_qkv (prep's
// activation pass was 144 MB of HBM traffic ~= 25 us; qkv is at 17% HBM and
// absorbs the f32 reads). B operand is now reg-staged from f32 inputs
// (coalesced dwordx4 -> cvt -> ds_write_b128, write-side XOR swizzle matching
// the read XOR), issued 3 iterations ahead with two named reg batches (full
// unroll -> static indexing). A stays global_load_lds with pre-swizzled
// source. Mixed vmcnt ledger per iter: F=8 + A=4 in flight -> steady
// vmcnt(12), tail 4 -> 0. MFMA split: ks=0 half overlaps ks=1 frag-read
// latency before the barrier. prep now transposes weights only (1024 blocks).

typedef unsigned short u16;
typedef __bf16 bf16_t;
typedef bf16_t bf16x8 __attribute__((ext_vector_type(8)));
typedef u16 u16x8 __attribute__((ext_vector_type(8)));
typedef float f32x4 __attribute__((ext_vector_type(4)));

#define DEVI static __device__ __forceinline__
#define MFMA16(a, b, c) __builtin_amdgcn_mfma_f32_16x16x32_bf16((a), (b), (c), 0, 0, 0)

DEVI void gload_lds16(const void* g, void* l) {
  __builtin_amdgcn_global_load_lds((__attribute__((address_space(1))) void*)g,
                                   (__attribute__((address_space(3))) void*)l, 16, 0, 0);
}

DEVI u16 f2bf(float x) {
  bf16_t b = (bf16_t)x;
  u16 u;
  __builtin_memcpy(&u, &b, 2);
  return u;
}

// ---------------------------------------------------------------------------
// prep: f32 W -> bf16 WT[n][k] via LDS 64x64 transpose (weights only).
__global__ __launch_bounds__(256) void prep(const float* __restrict__ Wq,
                                            const float* __restrict__ Wk,
                                            const float* __restrict__ Wv,
                                            const float* __restrict__ Wo,
                                            u16* __restrict__ ws) {
  __shared__ float T[64][65];
  int bx = blockIdx.x;
  int mat = bx >> 8, ti = bx & 255;
  int rb = ti >> 4, cb = ti & 15;
  const float* src = (mat == 0) ? Wq : (mat == 1) ? Wk : (mat == 2) ? Wv : Wo;
  u16* dst = ws + (size_t)mat * 1048576;
  // mat<3: W[h][kk][j] (h=rb, k-block=cb) -> WT[h*64+j][kk]
  // mat=3: Wo[d][c]    (d-block=rb, c-block=cb) -> WoT[c][d]
  int stride = (mat < 3) ? 64 : 1024;
  size_t srcBase = (mat < 3) ? ((size_t)rb * 65536 + cb * 4096)
                             : ((size_t)rb * 65536 + cb * 64);
  size_t dstBase = (mat < 3) ? ((size_t)rb * 65536 + cb * 64)
                             : ((size_t)cb * 65536 + rb * 64);
#pragma unroll
  for (int p = 0; p < 4; ++p) {
    int e = p * 256 + threadIdx.x;  // 0..1023 float4s of the 64x64 tile
    int rr = e >> 4, c4 = (e & 15) * 4;
    float4 vv = *(const float4*)(src + srcBase + (size_t)rr * stride + c4);
    T[rr][c4] = vv.x; T[rr][c4 + 1] = vv.y; T[rr][c4 + 2] = vv.z; T[rr][c4 + 3] = vv.w;
  }
  __syncthreads();
#pragma unroll
  for (int p = 0; p < 2; ++p) {
    int e = p * 256 + threadIdx.x;  // 0..511 ushort8 chunks
    int n = e >> 3, c8 = (e & 7) * 8;
    u16x8 o;
#pragma unroll
    for (int i = 0; i < 8; ++i) o[i] = f2bf(T[c8 + i][n]);
    *(u16x8*)(dst + dstBase + (size_t)n * 1024 + c8) = o;
  }
}

// ---------------------------------------------------------------------------
// QKV projections. D[m][n] = sum_k A[m][k] B_f32[n][k]. 128x128 tile, BK=64,
// double-buffered (64 KiB -> 2 blocks/CU), 4 waves (2x2), per-wave 64x64.
// Grid 1536 = 8m x 64n x 3z = 3 uniform residency rounds. A: bf16 WT via
// global_load_lds (pre-swizzled source). B: f32 activations reg-staged
// (dwordx4 x8 -> cvt -> ds_write_b128 x4, write-side XOR swizzle). F batches
// issued 3 iters ahead; vmcnt(12) steady / 4 / 0 tail.
__global__ __launch_bounds__(256, 2) void gemm_qkv(const u16* __restrict__ WT,
                                                   const float* __restrict__ qf,
                                                   const float* __restrict__ kf,
                                                   const float* __restrict__ vf,
                                                   u16* __restrict__ Qw,
                                                   u16* __restrict__ Kw,
                                                   u16* __restrict__ Vw) {
  __shared__ __align__(1024) u16 lds[2][2][8192];  // [buf][A,B][128*64]
  char* ldsc = (char*)lds;
  int tid = threadIdx.x;
  int wid = tid >> 6, lane = tid & 63, quad = lane >> 4, l16 = lane & 15;
  int wm = wid >> 1, wn = wid & 1;

  int id = blockIdx.x;                      // 0..1535 (1536 % 8 == 0, bijective)
  int wgid = (id & 7) * 192 + (id >> 3);    // XCD x owns wgid [192x, 192x+192)
  int mt = wgid & 7;                        // m fastest: 8 m-tiles share B panel
  int rest = wgid >> 3;                     // 0..191
  int nt = rest & 63;
  int z = rest >> 6;
  const u16* Ag = WT + (size_t)z * 1048576 + (size_t)mt * 131072;
  const float* Bg = ((z == 0) ? qf : (z == 1) ? kf : vf) + (size_t)nt * 131072;
  u16* out = (z == 0) ? Qw : (z == 1) ? Kw : Vw;
  float oscale = (z == 0) ? 0.125f : 1.0f;

  // A staging (gload_lds): chunk c = p*256+tid -> dest byte c*16 (linear);
  // row r = (tid>>3)+32p, phys chunk pc = tid&7, logical lc = pc^(r&7).
  int r0 = tid >> 3;
  int lcA = (tid ^ r0) & 7;
  size_t gbaseA = (size_t)r0 * 1024 + lcA * 8;
  // B staging (reg): slot s covers row s*32+r0, logical chunk c8 = tid&7;
  // f32 src fully linear; ds_write to phys chunk c8^(r0&7) (s*32 keeps r&7).
  int c8f = (tid & 7) * 8;
  int wxor = (((tid & 7) ^ (r0 & 7)) << 4);

  int rx = l16 & 7;  // read-side XOR
  int rowA = wm * 64 + l16;
  int rowB = wn * 64 + l16;

  auto stageA = [&](int buf, int kt) {
#pragma unroll
    for (int p = 0; p < 4; ++p)
      gload_lds16(Ag + gbaseA + (size_t)p * 32768 + kt * 64,
                  ldsc + buf * 32768 + p * 4096 + tid * 16);
  };
  auto rdA = [&](int buf, int mf, int ks) -> bf16x8 {
    return *(const bf16x8*)(ldsc + buf * 32768 + (rowA + mf * 16) * 128 +
                            ((((ks << 2) | quad) ^ rx) << 4));
  };
  auto rdB = [&](int buf, int nf, int ks) -> bf16x8 {
    return *(const bf16x8*)(ldsc + buf * 32768 + 16384 + (rowB + nf * 16) * 128 +
                            ((((ks << 2) | quad) ^ rx) << 4));
  };

  f32x4 acc[4][4];
#pragma unroll
  for (int i = 0; i < 4; ++i)
#pragma unroll
    for (int j = 0; j < 4; ++j) acc[i][j] = {0.f, 0.f, 0.f, 0.f};
  bf16x8 af[4][2], bfr[4][2];
  float4 fa[8], fb[8];

#define ISSUE_F(KT, F)                                                        \
  do {                                                                        \
    _Pragma("unroll") for (int s = 0; s < 4; ++s) {                           \
      const float* gp = Bg + (size_t)(s * 32 + r0) * 1024 + (KT) * 64 + c8f;  \
      F[2 * s] = *(const float4*)gp;                                          \
      F[2 * s + 1] = *(const float4*)(gp + 4);                                \
    }                                                                         \
  } while (0)

#define WRITE_B(BUF, F)                                                       \
  do {                                                                        \
    _Pragma("unroll") for (int s = 0; s < 4; ++s) {                           \
      u16x8 o;                                                                \
      o[0] = f2bf(F[2 * s].x); o[1] = f2bf(F[2 * s].y);                       \
      o[2] = f2bf(F[2 * s].z); o[3] = f2bf(F[2 * s].w);                       \
      o[4] = f2bf(F[2 * s + 1].x); o[5] = f2bf(F[2 * s + 1].y);               \
      o[6] = f2bf(F[2 * s + 1].z); o[7] = f2bf(F[2 * s + 1].w);               \
      *(u16x8*)(ldsc + (BUF) * 32768 + 16384 + (s * 32 + r0) * 128 + wxor) = o; \
    }                                                                         \
  } while (0)

  // prologue: F0->fa, F1->fb, A0, A1 issued; fill B0, B1; F2->fa in flight.
  ISSUE_F(0, fa);
  ISSUE_F(1, fb);
  stageA(0, 0);
  stageA(1, 1);
  asm volatile("s_waitcnt vmcnt(16)" ::: "memory");  // F0 landed
  WRITE_B(0, fa);
  ISSUE_F(2, fa);
  asm volatile("s_waitcnt vmcnt(16)" ::: "memory");  // F1 landed (keep A0,A1,F2)
  WRITE_B(1, fb);
  asm volatile("s_waitcnt vmcnt(12)" ::: "memory");  // A0 landed (keep A1,F2)
  asm volatile("s_waitcnt lgkmcnt(0)" ::: "memory");
  __builtin_amdgcn_s_barrier();

#define QKV_ITER(T, FC, FI)                                                   \
  do {                                                                        \
    constexpr int t_ = (T);                                                   \
    constexpr int cur = t_ & 1;                                               \
    if (t_ < 13) ISSUE_F(t_ + 3, FI);                                         \
    _Pragma("unroll") for (int mf = 0; mf < 4; ++mf)                          \
        af[mf][0] = rdA(cur, mf, 0);                                          \
    _Pragma("unroll") for (int nf = 0; nf < 4; ++nf)                          \
        bfr[nf][0] = rdB(cur, nf, 0);                                         \
    _Pragma("unroll") for (int mf = 0; mf < 4; ++mf)                          \
        af[mf][1] = rdA(cur, mf, 1);                                          \
    _Pragma("unroll") for (int nf = 0; nf < 4; ++nf)                          \
        bfr[nf][1] = rdB(cur, nf, 1);                                         \
    _Pragma("unroll") for (int mf = 0; mf < 4; ++mf)                          \
        _Pragma("unroll") for (int nf = 0; nf < 4; ++nf)                      \
            acc[mf][nf] = MFMA16(af[mf][0], bfr[nf][0], acc[mf][nf]);         \
    asm volatile("s_waitcnt lgkmcnt(0)" ::: "memory");                        \
    __builtin_amdgcn_s_barrier();                                             \
    if (t_ < 14) stageA(cur, t_ + 2);                                         \
    if (t_ < 13)                                                              \
      asm volatile("s_waitcnt vmcnt(12)" ::: "memory");                       \
    else if (t_ == 13)                                                        \
      asm volatile("s_waitcnt vmcnt(4)" ::: "memory");                        \
    else                                                                      \
      asm volatile("s_waitcnt vmcnt(0)" ::: "memory");                        \
    if (t_ < 14) WRITE_B(cur, FC);                                            \
    __builtin_amdgcn_s_setprio(1);                                            \
    _Pragma("unroll") for (int mf = 0; mf < 4; ++mf)                          \
        _Pragma("unroll") for (int nf = 0; nf < 4; ++nf)                      \
            acc[mf][nf] = MFMA16(af[mf][1], bfr[nf][1], acc[mf][nf]);         \
    __builtin_amdgcn_s_setprio(0);                                            \
    asm volatile("s_waitcnt lgkmcnt(0)" ::: "memory");                        \
    __builtin_amdgcn_s_barrier();                                             \
  } while (0)

  QKV_ITER(0, fa, fb);
  QKV_ITER(1, fb, fa);
  QKV_ITER(2, fa, fb);
  QKV_ITER(3, fb, fa);
  QKV_ITER(4, fa, fb);
  QKV_ITER(5, fb, fa);
  QKV_ITER(6, fa, fb);
  QKV_ITER(7, fb, fa);
  QKV_ITER(8, fa, fb);
  QKV_ITER(9, fb, fa);
  QKV_ITER(10, fa, fb);
  QKV_ITER(11, fb, fa);
  QKV_ITER(12, fa, fb);
  QKV_ITER(13, fb, fa);
  QKV_ITER(14, fa, fb);
  QKV_ITER(15, fb, fa);
#undef QKV_ITER
#undef ISSUE_F
#undef WRITE_B

#pragma unroll
  for (int mf = 0; mf < 4; ++mf) {
    int m = mt * 128 + wm * 64 + mf * 16 + quad * 4;
    int h = m >> 6, dk = m & 63;
#pragma unroll
    for (int nf = 0; nf < 4; ++nf) {
      int n = nt * 128 + wn * 64 + nf * 16 + l16;
      int bb = n >> 10, l = n & 1023;
      f32x4 vv = acc[mf][nf];
      if (z < 2) {
        ushort4 st;
        st.x = f2bf(vv[0] * oscale); st.y = f2bf(vv[1] * oscale);
        st.z = f2bf(vv[2] * oscale); st.w = f2bf(vv[3] * oscale);
        *(ushort4*)(out + ((size_t)((bb * 16 + h) * 1024 + l) * 64 + dk)) = st;
      } else {
        size_t base = ((size_t)((bb * 16 + h) * 64 + dk)) * 1024 + l;
        out[base] = f2bf(vv[0]);
        out[base + 1024] = f2bf(vv[1]);
        out[base + 2048] = f2bf(vv[2]);
        out[base + 3072] = f2bf(vv[3]);
      }
    }
  }
}

// ---------------------------------------------------------------------------
// Out-projection: f32 out[row][d] = sum_k WoT[d][k]*Cw[row][k] + bias[d].
// 128x128/BK=64 dbuf structure. Grid 512 = 8m x 64n = 1 uniform round.
__global__ __launch_bounds__(256, 2) void gemm_out(const u16* __restrict__ A,
                                                   const u16* __restrict__ Bx,
                                                   float* __restrict__ outf,
                                                   const float* __restrict__ bias) {
  __shared__ __align__(1024) u16 lds[2][2][8192];
  char* ldsc = (char*)lds;
  int tid = threadIdx.x;
  int wid = tid >> 6, lane = tid & 63, quad = lane >> 4, l16 = lane & 15;
  int wm = wid >> 1, wn = wid & 1;

  int id = blockIdx.x;                    // 0..511
  int wgid = (id & 7) * 64 + (id >> 3);   // xcd owns 64 consecutive
  int mt = wgid & 7;
  int nt = wgid >> 3;                     // 0..63, 8 per xcd
  const u16* Ag = A + (size_t)mt * 131072;
  const u16* Bg = Bx + (size_t)nt * 131072;

  int r0 = tid >> 3;
  int lc = (tid ^ r0) & 7;
  size_t gbase = (size_t)r0 * 1024 + lc * 8;
  int rx = l16 & 7;
  int rowA = wm * 64 + l16;
  int rowB = wn * 64 + l16;

  auto stage = [&](int buf, int kt) {
#pragma unroll
    for (int p = 0; p < 4; ++p)
      gload_lds16(Ag + gbase + (size_t)p * 32768 + kt * 64,
                  ldsc + buf * 32768 + p * 4096 + tid * 16);
#pragma unroll
    for (int p = 0; p < 4; ++p)
      gload_lds16(Bg + gbase + (size_t)p * 32768 + kt * 64,
                  ldsc + buf * 32768 + 16384 + p * 4096 + tid * 16);
  };
  auto rdA = [&](int buf, int mf, int ks) -> bf16x8 {
    return *(const bf16x8*)(ldsc + buf * 32768 + (rowA + mf * 16) * 128 +
                            ((((ks << 2) | quad) ^ rx) << 4));
  };
  auto rdB = [&](int buf, int nf, int ks) -> bf16x8 {
    return *(const bf16x8*)(ldsc + buf * 32768 + 16384 + (rowB + nf * 16) * 128 +
                            ((((ks << 2) | quad) ^ rx) << 4));
  };

  f32x4 acc[4][4];
#pragma unroll
  for (int i = 0; i < 4; ++i)
#pragma unroll
    for (int j = 0; j < 4; ++j) acc[i][j] = {0.f, 0.f, 0.f, 0.f};
  bf16x8 af[4][2], bfr[4][2];

  stage(0, 0);
  stage(1, 1);
  asm volatile("s_waitcnt vmcnt(8)" ::: "memory");
  __builtin_amdgcn_s_barrier();

  for (int t = 0; t < 16; ++t) {
    int cur = t & 1;
#pragma unroll
    for (int mf = 0; mf < 4; ++mf)
#pragma unroll
      for (int ks = 0; ks < 2; ++ks) af[mf][ks] = rdA(cur, mf, ks);
#pragma unroll
    for (int nf = 0; nf < 4; ++nf)
#pragma unroll
      for (int ks = 0; ks < 2; ++ks) bfr[nf][ks] = rdB(cur, nf, ks);
    asm volatile("s_waitcnt lgkmcnt(0)" ::: "memory");
    __builtin_amdgcn_s_barrier();
    if (t < 14) stage(cur, t + 2);
    __builtin_amdgcn_s_setprio(1);
#pragma unroll
    for (int ks = 0; ks < 2; ++ks)
#pragma unroll
      for (int mf = 0; mf < 4; ++mf)
#pragma unroll
        for (int nf = 0; nf < 4; ++nf)
          acc[mf][nf] = MFMA16(af[mf][ks], bfr[nf][ks], acc[mf][nf]);
    __builtin_amdgcn_s_setprio(0);
    if (t < 14)
      asm volatile("s_waitcnt vmcnt(8)" ::: "memory");
    else
      asm volatile("s_waitcnt vmcnt(0)" ::: "memory");
    __builtin_amdgcn_s_barrier();
  }

#pragma unroll
  for (int mf = 0; mf < 4; ++mf) {
    int m = mt * 128 + wm * 64 + mf * 16 + quad * 4;
    float4 bq = *(const float4*)(bias + m);
#pragma unroll
    for (int nf = 0; nf < 4; ++nf) {
      int n = nt * 128 + wn * 64 + nf * 16 + l16;
      f32x4 vv = acc[mf][nf];
      float4 st;
      st.x = vv[0] + bq.x;
      st.y = vv[1] + bq.y;
      st.z = vv[2] + bq.z;
      st.w = vv[3] + bq.w;
      *(float4*)(outf + ((size_t)n * 1024 + m)) = st;
    }
  }
}

// ---------------------------------------------------------------------------
// Attention: block = 4 waves, 128 q (wave owns 32 q = 2 B-frags).
// S^T = K Q^T (Q pre-scaled); exp (no max-sub); P in dead sQ region;
// O^T = V^T P^T. XCD swizzle: the 8 q-blocks of one (b,h) share K/V -> same XCD.
__global__ __launch_bounds__(256, 4) void attn_k(const u16* __restrict__ Q,
                                                 const u16* __restrict__ K,
                                                 const u16* __restrict__ VT,
                                                 u16* __restrict__ CTX) {
  __shared__ __align__(16) u16 sQ[128 * 64];  // 16 KB; reused as sP after bq load
  __shared__ __align__(16) u16 sK[64 * 64];   // 8 KB
  __shared__ __align__(16) u16 sV[64 * 64];   // 8 KB
  int tid = threadIdx.x;
  int wid = tid >> 6, lane = tid & 63, quad = lane >> 4, l16 = lane & 15;
  int id = blockIdx.x + 8 * blockIdx.y;  // 0..1023
  int xcd = id & 7, j = id >> 3;         // j: 0..127
  int qt = j & 7;
  int bh = xcd * 16 + (j >> 3);          // 0..127
  const u16* Qb = Q + (size_t)bh * 65536;
  const u16* Kb = K + (size_t)bh * 65536;
  const u16* Vb = VT + (size_t)bh * 65536;
  int q0 = qt * 128;

#pragma unroll
  for (int p = 0; p < 4; p++) {
    int cl = p * 256 + tid;
    int r = cl >> 3, c = cl & 7, g = c ^ (r & 7);
    gload_lds16(Qb + (size_t)(q0 + r) * 64 + g * 8, (char*)sQ + (p * 256 + wid * 64) * 16);
  }
  __syncthreads();

  bf16x8 bq[2][2];
#pragma unroll
  for (int qf = 0; qf < 2; qf++) {
    int row = wid * 32 + qf * 16 + l16;
#pragma unroll
    for (int ks = 0; ks < 2; ks++) {
      int ch = (ks * 4 + quad) ^ (row & 7);
      bq[qf][ks] = *(const bf16x8*)((const char*)sQ + row * 128 + ch * 16);
    }
  }
  // first K-loop barrier drains these reads before any sP write lands.

  u16* sPw = sQ + wid * 2048;  // per-wave 32 rows x 64 lk (4 KB)

  f32x4 oacc[4][2];
#pragma unroll
  for (int i = 0; i < 4; i++) {
    oacc[i][0] = {0.f, 0.f, 0.f, 0.f};
    oacc[i][1] = {0.f, 0.f, 0.f, 0.f};
  }
  float lsum[2] = {0.f, 0.f};

  for (int lk0 = 0; lk0 < 1024; lk0 += 64) {
#pragma unroll
    for (int p = 0; p < 2; p++) {
      int cl = p * 256 + tid;
      int r = cl >> 3, c = cl & 7, g = c ^ (r & 7);
      gload_lds16(Kb + (size_t)(lk0 + r) * 64 + g * 8, (char*)sK + (p * 256 + wid * 64) * 16);
      gload_lds16(Vb + (size_t)r * 1024 + lk0 + g * 8, (char*)sV + (p * 256 + wid * 64) * 16);
    }
    __syncthreads();

    f32x4 s[4][2];
#pragma unroll
    for (int mt = 0; mt < 4; mt++) {
      s[mt][0] = {0.f, 0.f, 0.f, 0.f};
      s[mt][1] = {0.f, 0.f, 0.f, 0.f};
    }
#pragma unroll
    for (int ks = 0; ks < 2; ks++) {
#pragma unroll
      for (int mt = 0; mt < 4; mt++) {
        int row = mt * 16 + l16;
        int ch = (ks * 4 + quad) ^ (row & 7);
        bf16x8 a = *(const bf16x8*)((const char*)sK + row * 128 + ch * 16);
        s[mt][0] = MFMA16(a, bq[0][ks], s[mt][0]);
        s[mt][1] = MFMA16(a, bq[1][ks], s[mt][1]);
      }
    }

#pragma unroll
    for (int qf = 0; qf < 2; qf++) {
      int row = qf * 16 + l16;
#pragma unroll
      for (int mt = 0; mt < 4; mt++) {
        float p0 = __expf(s[mt][qf][0]);
        float p1 = __expf(s[mt][qf][1]);
        float p2 = __expf(s[mt][qf][2]);
        float p3 = __expf(s[mt][qf][3]);
        lsum[qf] += (p0 + p1) + (p2 + p3);
        ushort4 st;
        st.x = f2bf(p0); st.y = f2bf(p1); st.z = f2bf(p2); st.w = f2bf(p3);
        int ch = (2 * mt + (quad >> 1)) ^ (row & 7);
        *(ushort4*)((char*)sPw + row * 128 + ch * 16 + (quad & 1) * 8) = st;
      }
    }
    asm volatile("s_waitcnt lgkmcnt(0)" ::: "memory");  // same-wave P write->read

    bf16x8 bp[2][2];
#pragma unroll
    for (int qf = 0; qf < 2; qf++) {
      int row = qf * 16 + l16;
#pragma unroll
      for (int c = 0; c < 2; c++) {
        int ch = (c * 4 + quad) ^ (row & 7);
        bp[qf][c] = *(const bf16x8*)((const char*)sPw + row * 128 + ch * 16);
      }
    }
#pragma unroll
    for (int c = 0; c < 2; c++) {
#pragma unroll
      for (int mt = 0; mt < 4; mt++) {
        int row = mt * 16 + l16;
        int ch = (c * 4 + quad) ^ (row & 7);
        bf16x8 a = *(const bf16x8*)((const char*)sV + row * 128 + ch * 16);
        oacc[mt][0] = MFMA16(a, bp[0][c], oacc[mt][0]);
        oacc[mt][1] = MFMA16(a, bp[1][c], oacc[mt][1]);
      }
    }
    __syncthreads();
  }

#pragma unroll
  for (int qf = 0; qf < 2; qf++) {
    lsum[qf] += __shfl_xor(lsum[qf], 16, 64);
    lsum[qf] += __shfl_xor(lsum[qf], 32, 64);
  }
  float inv0 = 1.f / lsum[0], inv1 = 1.f / lsum[1];

  int b = bh >> 4, h = bh & 15;
#pragma unroll
  for (int qf = 0; qf < 2; qf++) {
    int qg = q0 + wid * 32 + qf * 16 + l16;
    float inv = qf ? inv1 : inv0;
#pragma unroll
    for (int mt = 0; mt < 4; mt++) {
      int dk = mt * 16 + quad * 4;
      ushort4 st;
      st.x = f2bf(oacc[mt][qf][0] * inv);
      st.y = f2bf(oacc[mt][qf][1] * inv);
      st.z = f2bf(oacc[mt][qf][2] * inv);
      st.w = f2bf(oacc[mt][qf][3] * inv);
      *(ushort4*)(CTX + (((size_t)(b * 1024 + qg) * 16 + h) * 64 + dk)) = st;
    }
  }
}

// ---------------------------------------------------------------------------
extern "C" void kernel_launch(void* const* d_in, const int* in_sizes, int n_in,
                              void* d_out, int out_size, void* d_ws, size_t ws_size,
                              hipStream_t stream) {
  (void)in_sizes; (void)n_in; (void)out_size;
  const float* query = (const float*)d_in[0];
  const float* key_ = (const float*)d_in[1];
  const float* value = (const float*)d_in[2];
  const float* Wq = (const float*)d_in[3];
  const float* Wk = (const float*)d_in[4];
  const float* Wv = (const float*)d_in[5];
  const float* Wo = (const float*)d_in[6];
  const float* bo = (const float*)d_in[7];

  u16* ws = (u16*)d_ws;
  u16* WT = ws;                   // 4 x [1024][1024] bf16 (WTq,WTk,WTv,WoT)
  u16* Cw = ws + 4194304;         // [8192][1024] bf16 ctx (attn out)
  u16* Qw = ws + 29360128;        // [B,H,L,DK]
  u16* Kw = ws + 37748736;        // [B,H,L,DK]
  u16* Vw = ws + 46137344;        // [B,H,DK,L]
  float* outp = (float*)d_out;

  prep<<<1024, 256, 0, stream>>>(Wq, Wk, Wv, Wo, ws);
  gemm_qkv<<<dim3(1536), 256, 0, stream>>>(WT, query, key_, value, Qw, Kw, Vw);
  attn_k<<<dim3(8, 128), 256, 0, stream>>>(Qw, Kw, Vw, Cw);
  gemm_out<<<dim3(512), 256, 0, stream>>>(WT + 3145728, Cw, outp, bo);
}

// Round 4
// 274.993 us; speedup vs baseline: 1.1181x; 1.1181x over previous
//
#include <hip/hip_runtime.h>
#include <hip/hip_bf16.h>
#include <stdint.h>

// LatticeMultiHeadAttention on MI355X (gfx950). f32 in/out, bf16 MFMA inside.
// Kuramoto phase inputs are softmax-shift-invariant -> unused.
//
// R8: revert R7's qkv fusion (reg-staged B regressed 57.6->112.7 us, = m151's
// documented reg-staging-vs-gload_lds loss; prep restored to R6 form).
// New: attn_k pipelined. R6 attn was single-buffered with a full
// vmcnt(0)+lgkm(0) drain (__syncthreads) every iter -> ~150 us by accounting
// (total - qkv - prep - out). Now: K double-buffered across iters (staged 2
// ahead), V prefetched at iter top (latency hides under QK^T+exp), LDS
// 16+16+8=40KB -> still 4 blocks/CU, all 1024 blocks resident. Counted
// waits: prologue vmcnt(2); per-iter single vmcnt(0) that drains only
// K(t+1)+V(t), both issued ~600cy earlier. setprio(1) around MFMA clusters
// (4 blocks/CU at independent phases = the regime where it pays).

typedef unsigned short u16;
typedef __bf16 bf16_t;
typedef bf16_t bf16x8 __attribute__((ext_vector_type(8)));
typedef u16 u16x8 __attribute__((ext_vector_type(8)));
typedef float f32x4 __attribute__((ext_vector_type(4)));

#define DEVI static __device__ __forceinline__
#define MFMA16(a, b, c) __builtin_amdgcn_mfma_f32_16x16x32_bf16((a), (b), (c), 0, 0, 0)

DEVI void gload_lds16(const void* g, void* l) {
  __builtin_amdgcn_global_load_lds((__attribute__((address_space(1))) void*)g,
                                   (__attribute__((address_space(3))) void*)l, 16, 0, 0);
}

DEVI u16 f2bf(float x) {
  bf16_t b = (bf16_t)x;
  u16 u;
  __builtin_memcpy(&u, &b, 2);
  return u;
}

// ---------------------------------------------------------------------------
// prep: [blocks 0..1023]   f32 W -> bf16 WT[n][k] via LDS 64x64 transpose
//       [blocks 1024..25599] f32 activations -> bf16 X copies (vectorized)
__global__ __launch_bounds__(256) void prep(const float* __restrict__ Wq,
                                            const float* __restrict__ Wk,
                                            const float* __restrict__ Wv,
                                            const float* __restrict__ Wo,
                                            const float* __restrict__ q,
                                            const float* __restrict__ k,
                                            const float* __restrict__ v,
                                            u16* __restrict__ ws) {
  int bx = blockIdx.x;
  if (bx < 1024) {
    __shared__ float T[64][65];
    int mat = bx >> 8, ti = bx & 255;
    int rb = ti >> 4, cb = ti & 15;
    const float* src = (mat == 0) ? Wq : (mat == 1) ? Wk : (mat == 2) ? Wv : Wo;
    u16* dst = ws + (size_t)mat * 1048576;
    // mat<3: W[h][kk][j] (h=rb, k-block=cb) -> WT[h*64+j][kk]
    // mat=3: Wo[d][c]    (d-block=rb, c-block=cb) -> WoT[c][d]
    int stride = (mat < 3) ? 64 : 1024;
    size_t srcBase = (mat < 3) ? ((size_t)rb * 65536 + cb * 4096)
                               : ((size_t)rb * 65536 + cb * 64);
    size_t dstBase = (mat < 3) ? ((size_t)rb * 65536 + cb * 64)
                               : ((size_t)cb * 65536 + rb * 64);
#pragma unroll
    for (int p = 0; p < 4; ++p) {
      int e = p * 256 + threadIdx.x;  // 0..1023 float4s of the 64x64 tile
      int rr = e >> 4, c4 = (e & 15) * 4;
      float4 vv = *(const float4*)(src + srcBase + (size_t)rr * stride + c4);
      T[rr][c4] = vv.x; T[rr][c4 + 1] = vv.y; T[rr][c4 + 2] = vv.z; T[rr][c4 + 3] = vv.w;
    }
    __syncthreads();
#pragma unroll
    for (int p = 0; p < 2; ++p) {
      int e = p * 256 + threadIdx.x;  // 0..511 ushort8 chunks
      int n = e >> 3, c8 = (e & 7) * 8;
      u16x8 o;
#pragma unroll
      for (int i = 0; i < 8; ++i) o[i] = f2bf(T[c8 + i][n]);
      *(u16x8*)(dst + dstBase + (size_t)n * 1024 + c8) = o;
    }
  } else {
    int id = (bx - 1024) * 256 + threadIdx.x;  // 0..6291455, 4 elems each
    int t = id >> 21;
    size_t rem = (size_t)(id & 2097151) * 4;
    const float* src = (t == 0) ? q : (t == 1) ? k : v;
    float4 a = *(const float4*)(src + rem);
    ushort4 st;
    st.x = f2bf(a.x); st.y = f2bf(a.y); st.z = f2bf(a.z); st.w = f2bf(a.w);
    *(ushort4*)(ws + 4194304 + (size_t)t * 8388608 + rem) = st;
  }
}

// ---------------------------------------------------------------------------
// QKV projections. D[m][n] = sum_k A[m][k] B[n][k]. 128x128 tile, BK=64,
// double-buffered (64 KiB -> 2 blocks/CU), 4 waves (2x2), per-wave 64x64.
// Grid 1536 = 8m x 64n x 3z = 3 uniform residency rounds. Counted vmcnt(8);
// drain vmcnt(0) only on the last two iterations. Chunk-XOR swizzle: logical
// chunk c of row r at physical c^(r&7); staging pre-swizzles the global
// source (linear LDS dest), reads XOR the same.
__global__ __launch_bounds__(256, 2) void gemm_qkv(const u16* __restrict__ WT,
                                                   const u16* __restrict__ X,
                                                   u16* __restrict__ Qw,
                                                   u16* __restrict__ Kw,
                                                   u16* __restrict__ Vw) {
  __shared__ __align__(1024) u16 lds[2][2][8192];  // [buf][A,B][128*64]
  char* ldsc = (char*)lds;
  int tid = threadIdx.x;
  int wid = tid >> 6, lane = tid & 63, quad = lane >> 4, l16 = lane & 15;
  int wm = wid >> 1, wn = wid & 1;

  int id = blockIdx.x;                      // 0..1535 (1536 % 8 == 0, bijective)
  int wgid = (id & 7) * 192 + (id >> 3);    // XCD x owns wgid [192x, 192x+192)
  int mt = wgid & 7;                        // m fastest: 8 m-tiles share B panel
  int rest = wgid >> 3;                     // 0..191
  int nt = rest & 63;
  int z = rest >> 6;
  const u16* Ag = WT + (size_t)z * 1048576 + (size_t)mt * 131072;
  const u16* Bg = X + (size_t)z * 8388608 + (size_t)nt * 131072;
  u16* out = (z == 0) ? Qw : (z == 1) ? Kw : Vw;
  float oscale = (z == 0) ? 0.125f : 1.0f;

  // staging invariants: chunk c = p*256+tid -> dest byte c*16 (linear);
  // row r = c>>3 = (tid>>3)+32p, phys chunk pc = tid&7, logical lc = pc^(r&7)
  int r0 = tid >> 3;
  int lc = (tid ^ r0) & 7;
  size_t gbase = (size_t)r0 * 1024 + lc * 8;

  int rx = l16 & 7;  // read-side XOR (row&7 == l16&7; row bases are x16)
  int rowA = wm * 64 + l16;
  int rowB = wn * 64 + l16;

  auto stage = [&](int buf, int kt) {
#pragma unroll
    for (int p = 0; p < 4; ++p)
      gload_lds16(Ag + gbase + (size_t)p * 32768 + kt * 64,
                  ldsc + buf * 32768 + p * 4096 + tid * 16);
#pragma unroll
    for (int p = 0; p < 4; ++p)
      gload_lds16(Bg + gbase + (size_t)p * 32768 + kt * 64,
                  ldsc + buf * 32768 + 16384 + p * 4096 + tid * 16);
  };
  auto rdA = [&](int buf, int mf, int ks) -> bf16x8 {
    return *(const bf16x8*)(ldsc + buf * 32768 + (rowA + mf * 16) * 128 +
                            ((((ks << 2) | quad) ^ rx) << 4));
  };
  auto rdB = [&](int buf, int nf, int ks) -> bf16x8 {
    return *(const bf16x8*)(ldsc + buf * 32768 + 16384 + (rowB + nf * 16) * 128 +
                            ((((ks << 2) | quad) ^ rx) << 4));
  };

  f32x4 acc[4][4];
#pragma unroll
  for (int i = 0; i < 4; ++i)
#pragma unroll
    for (int j = 0; j < 4; ++j) acc[i][j] = {0.f, 0.f, 0.f, 0.f};
  bf16x8 af[4][2], bfr[4][2];

  stage(0, 0);
  stage(1, 1);
  asm volatile("s_waitcnt vmcnt(8)" ::: "memory");  // kt0 landed, kt1 in flight
  __builtin_amdgcn_s_barrier();

  for (int t = 0; t < 16; ++t) {
    int cur = t & 1;
#pragma unroll
    for (int mf = 0; mf < 4; ++mf)
#pragma unroll
      for (int ks = 0; ks < 2; ++ks) af[mf][ks] = rdA(cur, mf, ks);
#pragma unroll
    for (int nf = 0; nf < 4; ++nf)
#pragma unroll
      for (int ks = 0; ks < 2; ++ks) bfr[nf][ks] = rdB(cur, nf, ks);
    asm volatile("s_waitcnt lgkmcnt(0)" ::: "memory");  // reads retired
    __builtin_amdgcn_s_barrier();                       // all waves done with cur
    if (t < 14) stage(cur, t + 2);                      // overwrite cur <- kt t+2
    __builtin_amdgcn_s_setprio(1);
#pragma unroll
    for (int ks = 0; ks < 2; ++ks)
#pragma unroll
      for (int mf = 0; mf < 4; ++mf)
#pragma unroll
        for (int nf = 0; nf < 4; ++nf)
          acc[mf][nf] = MFMA16(af[mf][ks], bfr[nf][ks], acc[mf][nf]);
    __builtin_amdgcn_s_setprio(0);
    // steady state: 16 outstanding (kt t+2 new, kt t+1 old); vmcnt(8) -> kt t+1
    // landed for next iter. Last two iters: drain.
    if (t < 14)
      asm volatile("s_waitcnt vmcnt(8)" ::: "memory");
    else
      asm volatile("s_waitcnt vmcnt(0)" ::: "memory");
    __builtin_amdgcn_s_barrier();
  }

#pragma unroll
  for (int mf = 0; mf < 4; ++mf) {
    int m = mt * 128 + wm * 64 + mf * 16 + quad * 4;
    int h = m >> 6, dk = m & 63;
#pragma unroll
    for (int nf = 0; nf < 4; ++nf) {
      int n = nt * 128 + wn * 64 + nf * 16 + l16;
      int bb = n >> 10, l = n & 1023;
      f32x4 vv = acc[mf][nf];
      if (z < 2) {
        ushort4 st;
        st.x = f2bf(vv[0] * oscale); st.y = f2bf(vv[1] * oscale);
        st.z = f2bf(vv[2] * oscale); st.w = f2bf(vv[3] * oscale);
        *(ushort4*)(out + ((size_t)((bb * 16 + h) * 1024 + l) * 64 + dk)) = st;
      } else {
        size_t base = ((size_t)((bb * 16 + h) * 64 + dk)) * 1024 + l;
        out[base] = f2bf(vv[0]);
        out[base + 1024] = f2bf(vv[1]);
        out[base + 2048] = f2bf(vv[2]);
        out[base + 3072] = f2bf(vv[3]);
      }
    }
  }
}

// ---------------------------------------------------------------------------
// Out-projection: f32 out[row][d] = sum_k WoT[d][k]*Cw[row][k] + bias[d].
// Same 128x128/BK=64 dbuf structure. Grid 512 = 8m x 64n = 1 uniform round.
__global__ __launch_bounds__(256, 2) void gemm_out(const u16* __restrict__ A,
                                                   const u16* __restrict__ Bx,
                                                   float* __restrict__ outf,
                                                   const float* __restrict__ bias) {
  __shared__ __align__(1024) u16 lds[2][2][8192];
  char* ldsc = (char*)lds;
  int tid = threadIdx.x;
  int wid = tid >> 6, lane = tid & 63, quad = lane >> 4, l16 = lane & 15;
  int wm = wid >> 1, wn = wid & 1;

  int id = blockIdx.x;                    // 0..511
  int wgid = (id & 7) * 64 + (id >> 3);   // xcd owns 64 consecutive
  int mt = wgid & 7;
  int nt = wgid >> 3;                     // 0..63, 8 per xcd
  const u16* Ag = A + (size_t)mt * 131072;
  const u16* Bg = Bx + (size_t)nt * 131072;

  int r0 = tid >> 3;
  int lc = (tid ^ r0) & 7;
  size_t gbase = (size_t)r0 * 1024 + lc * 8;
  int rx = l16 & 7;
  int rowA = wm * 64 + l16;
  int rowB = wn * 64 + l16;

  auto stage = [&](int buf, int kt) {
#pragma unroll
    for (int p = 0; p < 4; ++p)
      gload_lds16(Ag + gbase + (size_t)p * 32768 + kt * 64,
                  ldsc + buf * 32768 + p * 4096 + tid * 16);
#pragma unroll
    for (int p = 0; p < 4; ++p)
      gload_lds16(Bg + gbase + (size_t)p * 32768 + kt * 64,
                  ldsc + buf * 32768 + 16384 + p * 4096 + tid * 16);
  };
  auto rdA = [&](int buf, int mf, int ks) -> bf16x8 {
    return *(const bf16x8*)(ldsc + buf * 32768 + (rowA + mf * 16) * 128 +
                            ((((ks << 2) | quad) ^ rx) << 4));
  };
  auto rdB = [&](int buf, int nf, int ks) -> bf16x8 {
    return *(const bf16x8*)(ldsc + buf * 32768 + 16384 + (rowB + nf * 16) * 128 +
                            ((((ks << 2) | quad) ^ rx) << 4));
  };

  f32x4 acc[4][4];
#pragma unroll
  for (int i = 0; i < 4; ++i)
#pragma unroll
    for (int j = 0; j < 4; ++j) acc[i][j] = {0.f, 0.f, 0.f, 0.f};
  bf16x8 af[4][2], bfr[4][2];

  stage(0, 0);
  stage(1, 1);
  asm volatile("s_waitcnt vmcnt(8)" ::: "memory");
  __builtin_amdgcn_s_barrier();

  for (int t = 0; t < 16; ++t) {
    int cur = t & 1;
#pragma unroll
    for (int mf = 0; mf < 4; ++mf)
#pragma unroll
      for (int ks = 0; ks < 2; ++ks) af[mf][ks] = rdA(cur, mf, ks);
#pragma unroll
    for (int nf = 0; nf < 4; ++nf)
#pragma unroll
      for (int ks = 0; ks < 2; ++ks) bfr[nf][ks] = rdB(cur, nf, ks);
    asm volatile("s_waitcnt lgkmcnt(0)" ::: "memory");
    __builtin_amdgcn_s_barrier();
    if (t < 14) stage(cur, t + 2);
    __builtin_amdgcn_s_setprio(1);
#pragma unroll
    for (int ks = 0; ks < 2; ++ks)
#pragma unroll
      for (int mf = 0; mf < 4; ++mf)
#pragma unroll
        for (int nf = 0; nf < 4; ++nf)
          acc[mf][nf] = MFMA16(af[mf][ks], bfr[nf][ks], acc[mf][nf]);
    __builtin_amdgcn_s_setprio(0);
    if (t < 14)
      asm volatile("s_waitcnt vmcnt(8)" ::: "memory");
    else
      asm volatile("s_waitcnt vmcnt(0)" ::: "memory");
    __builtin_amdgcn_s_barrier();
  }

#pragma unroll
  for (int mf = 0; mf < 4; ++mf) {
    int m = mt * 128 + wm * 64 + mf * 16 + quad * 4;
    float4 bq = *(const float4*)(bias + m);
#pragma unroll
    for (int nf = 0; nf < 4; ++nf) {
      int n = nt * 128 + wn * 64 + nf * 16 + l16;
      f32x4 vv = acc[mf][nf];
      float4 st;
      st.x = vv[0] + bq.x;
      st.y = vv[1] + bq.y;
      st.z = vv[2] + bq.z;
      st.w = vv[3] + bq.w;
      *(float4*)(outf + ((size_t)n * 1024 + m)) = st;
    }
  }
}

// ---------------------------------------------------------------------------
// Attention: block = 4 waves, 128 q (wave owns 32 q = 2 B-frags).
// S^T = K Q^T (Q pre-scaled); exp (no max-sub); P in dead sQ region;
// O^T = V^T P^T. XCD swizzle: the 8 q-blocks of one (b,h) share K/V.
// R8 pipeline: K double-buffered (staged 2 tiles ahead, across end barrier);
// V prefetched at iter top (latency hidden by QK^T+exp); one vmcnt(0) +
// 2 barriers per iter instead of a full-drain __syncthreads at iter top.
// LDS 16(sQ/sP) + 16(sK dbuf) + 8(sV) = 40 KB -> 4 blocks/CU, 1024 resident.
__global__ __launch_bounds__(256, 4) void attn_k(const u16* __restrict__ Q,
                                                 const u16* __restrict__ K,
                                                 const u16* __restrict__ VT,
                                                 u16* __restrict__ CTX) {
  __shared__ __align__(16) u16 sQ[128 * 64];     // 16 KB; reused as sP
  __shared__ __align__(16) u16 sK[2][64 * 64];   // 16 KB (dbuf)
  __shared__ __align__(16) u16 sV[64 * 64];      // 8 KB
  int tid = threadIdx.x;
  int wid = tid >> 6, lane = tid & 63, quad = lane >> 4, l16 = lane & 15;
  int id = blockIdx.x + 8 * blockIdx.y;  // 0..1023
  int xcd = id & 7, j = id >> 3;         // j: 0..127
  int qt = j & 7;
  int bh = xcd * 16 + (j >> 3);          // 0..127
  const u16* Qb = Q + (size_t)bh * 65536;
  const u16* Kb = K + (size_t)bh * 65536;
  const u16* Vb = VT + (size_t)bh * 65536;
  int q0 = qt * 128;

  auto stageK = [&](int buf, int lk0) {
#pragma unroll
    for (int p = 0; p < 2; ++p) {
      int cl = p * 256 + tid;
      int r = cl >> 3, c = cl & 7, g = c ^ (r & 7);
      gload_lds16(Kb + (size_t)(lk0 + r) * 64 + g * 8,
                  (char*)sK + buf * 8192 + (p * 256 + wid * 64) * 16);
    }
  };
  auto stageV = [&](int lk0) {
#pragma unroll
    for (int p = 0; p < 2; ++p) {
      int cl = p * 256 + tid;
      int r = cl >> 3, c = cl & 7, g = c ^ (r & 7);
      gload_lds16(Vb + (size_t)r * 1024 + lk0 + g * 8,
                  (char*)sV + (p * 256 + wid * 64) * 16);
    }
  };

  // prologue: Q (4 loads), K tile 0 and 1 (2+2 loads).
#pragma unroll
  for (int p = 0; p < 4; p++) {
    int cl = p * 256 + tid;
    int r = cl >> 3, c = cl & 7, g = c ^ (r & 7);
    gload_lds16(Qb + (size_t)(q0 + r) * 64 + g * 8, (char*)sQ + (p * 256 + wid * 64) * 16);
  }
  stageK(0, 0);
  stageK(1, 64);
  asm volatile("s_waitcnt vmcnt(2)" ::: "memory");  // Q + K0 landed; K1 in flight
  __builtin_amdgcn_s_barrier();

  bf16x8 bq[2][2];
#pragma unroll
  for (int qf = 0; qf < 2; qf++) {
    int row = wid * 32 + qf * 16 + l16;
#pragma unroll
    for (int ks = 0; ks < 2; ks++) {
      int ch = (ks * 4 + quad) ^ (row & 7);
      bq[qf][ks] = *(const bf16x8*)((const char*)sQ + row * 128 + ch * 16);
    }
  }
  // sP overwrite of these rows is data-dependent on QK^T MFMAs consuming bq
  // (same wave, in-order DS) -> no barrier needed.

  u16* sPw = sQ + wid * 2048;  // per-wave 32 rows x 64 lk (4 KB)

  f32x4 oacc[4][2];
#pragma unroll
  for (int i = 0; i < 4; i++) {
    oacc[i][0] = {0.f, 0.f, 0.f, 0.f};
    oacc[i][1] = {0.f, 0.f, 0.f, 0.f};
  }
  float lsum[2] = {0.f, 0.f};

  for (int t = 0; t < 16; ++t) {
    int cur = t & 1;
    stageV(t * 64);  // landed by the mid vmcnt(0); hidden under QK^T+exp

    f32x4 s[4][2];
#pragma unroll
    for (int mt = 0; mt < 4; mt++) {
      s[mt][0] = {0.f, 0.f, 0.f, 0.f};
      s[mt][1] = {0.f, 0.f, 0.f, 0.f};
    }
    __builtin_amdgcn_s_setprio(1);
#pragma unroll
    for (int ks = 0; ks < 2; ks++) {
#pragma unroll
      for (int mt = 0; mt < 4; mt++) {
        int row = mt * 16 + l16;
        int ch = (ks * 4 + quad) ^ (row & 7);
        bf16x8 a = *(const bf16x8*)((const char*)sK + cur * 8192 + row * 128 + ch * 16);
        s[mt][0] = MFMA16(a, bq[0][ks], s[mt][0]);
        s[mt][1] = MFMA16(a, bq[1][ks], s[mt][1]);
      }
    }
    __builtin_amdgcn_s_setprio(0);

#pragma unroll
    for (int qf = 0; qf < 2; qf++) {
      int row = qf * 16 + l16;
#pragma unroll
      for (int mt = 0; mt < 4; mt++) {
        float p0 = __expf(s[mt][qf][0]);
        float p1 = __expf(s[mt][qf][1]);
        float p2 = __expf(s[mt][qf][2]);
        float p3 = __expf(s[mt][qf][3]);
        lsum[qf] += (p0 + p1) + (p2 + p3);
        ushort4 st;
        st.x = f2bf(p0); st.y = f2bf(p1); st.z = f2bf(p2); st.w = f2bf(p3);
        int ch = (2 * mt + (quad >> 1)) ^ (row & 7);
        *(ushort4*)((char*)sPw + row * 128 + ch * 16 + (quad & 1) * 8) = st;
      }
    }
    asm volatile("s_waitcnt lgkmcnt(0)" ::: "memory");  // same-wave P write->read
                                                        // (also retires sK reads)
    bf16x8 bp[2][2];
#pragma unroll
    for (int qf = 0; qf < 2; qf++) {
      int row = qf * 16 + l16;
#pragma unroll
      for (int c = 0; c < 2; c++) {
        int ch = (c * 4 + quad) ^ (row & 7);
        bp[qf][c] = *(const bf16x8*)((const char*)sPw + row * 128 + ch * 16);
      }
    }
    // outstanding loads: K(t+1) [issued last iter] + V(t) [top of this iter]
    asm volatile("s_waitcnt vmcnt(0)" ::: "memory");
    __builtin_amdgcn_s_barrier();  // mid: V(t)/K(t+1) visible; sK[cur] reads done
    if (t < 14) stageK(cur, (t + 2) * 64);  // flies during PV + next QK^T

    __builtin_amdgcn_s_setprio(1);
#pragma unroll
    for (int c = 0; c < 2; c++) {
#pragma unroll
      for (int mt = 0; mt < 4; mt++) {
        int row = mt * 16 + l16;
        int ch = (c * 4 + quad) ^ (row & 7);
        bf16x8 a = *(const bf16x8*)((const char*)sV + row * 128 + ch * 16);
        oacc[mt][0] = MFMA16(a, bp[0][c], oacc[mt][0]);
        oacc[mt][1] = MFMA16(a, bp[1][c], oacc[mt][1]);
      }
    }
    __builtin_amdgcn_s_setprio(0);
    asm volatile("s_waitcnt lgkmcnt(0)" ::: "memory");  // sV reads retired
    __builtin_amdgcn_s_barrier();  // end: sV safe to overwrite next iter
  }

#pragma unroll
  for (int qf = 0; qf < 2; qf++) {
    lsum[qf] += __shfl_xor(lsum[qf], 16, 64);
    lsum[qf] += __shfl_xor(lsum[qf], 32, 64);
  }
  float inv0 = 1.f / lsum[0], inv1 = 1.f / lsum[1];

  int b = bh >> 4, h = bh & 15;
#pragma unroll
  for (int qf = 0; qf < 2; qf++) {
    int qg = q0 + wid * 32 + qf * 16 + l16;
    float inv = qf ? inv1 : inv0;
#pragma unroll
    for (int mt = 0; mt < 4; mt++) {
      int dk = mt * 16 + quad * 4;
      ushort4 st;
      st.x = f2bf(oacc[mt][qf][0] * inv);
      st.y = f2bf(oacc[mt][qf][1] * inv);
      st.z = f2bf(oacc[mt][qf][2] * inv);
      st.w = f2bf(oacc[mt][qf][3] * inv);
      *(ushort4*)(CTX + (((size_t)(b * 1024 + qg) * 16 + h) * 64 + dk)) = st;
    }
  }
}

// ---------------------------------------------------------------------------
extern "C" void kernel_launch(void* const* d_in, const int* in_sizes, int n_in,
                              void* d_out, int out_size, void* d_ws, size_t ws_size,
                              hipStream_t stream) {
  (void)in_sizes; (void)n_in; (void)out_size;
  const float* query = (const float*)d_in[0];
  const float* key_ = (const float*)d_in[1];
  const float* value = (const float*)d_in[2];
  const float* Wq = (const float*)d_in[3];
  const float* Wk = (const float*)d_in[4];
  const float* Wv = (const float*)d_in[5];
  const float* Wo = (const float*)d_in[6];
  const float* bo = (const float*)d_in[7];

  u16* ws = (u16*)d_ws;
  u16* WT = ws;                   // 4 x [1024][1024] bf16 (WTq,WTk,WTv,WoT)
  u16* X = ws + 4194304;          // 3 x [8192][1024] bf16 (Xq,Xk,Xv)
  u16* Qw = ws + 29360128;        // [B,H,L,DK]
  u16* Kw = ws + 37748736;        // [B,H,L,DK]
  u16* Vw = ws + 46137344;        // [B,H,DK,L]
  u16* Cw = X;                    // alias Xq (dead after projections)
  float* outp = (float*)d_out;

  prep<<<25600, 256, 0, stream>>>(Wq, Wk, Wv, Wo, query, key_, value, ws);
  // ws requirement: (46137344 + 8388608) u16 = 109051904 B
  gemm_qkv<<<dim3(1536), 256, 0, stream>>>(WT, X, Qw, Kw, Vw);
  attn_k<<<dim3(8, 128), 256, 0, stream>>>(Qw, Kw, Vw, Cw);
  gemm_out<<<dim3(512), 256, 0, stream>>>(WT + 3145728, Cw, outp, bo);
}